// Round 4
// baseline (36393.802 us; speedup 1.0000x reference)
//
#include <hip/hip_runtime.h>

#define T_LEN 16384
#define NT 1024
#define NBLK 64
#define CPB 16      // columns per block (4 per wave)
#define NTHR 256    // 4 waves

typedef unsigned long long u64;
typedef unsigned int u32;

// ws layout:
//   u64 buf0[1024] @ bytes [0,8192)      tagged alpha, even parity
//   u64 buf1[1024] @ bytes [8192,16384)  tagged alpha, odd parity
//   float gold     @ float index 4096
// tagged word = (step_tag << 32) | float_bits

__device__ __forceinline__ u64 pack_tag(u32 tag, float v) {
  return ((u64)tag << 32) | (u64)__float_as_uint(v);
}
__device__ __forceinline__ u64 ld_tag(const u64* p) {
  return __hip_atomic_load(p, __ATOMIC_RELAXED, __HIP_MEMORY_SCOPE_AGENT);
}
__device__ __forceinline__ void st_tag(u64* p, u64 v) {
  __hip_atomic_store(p, v, __ATOMIC_RELAXED, __HIP_MEMORY_SCOPE_AGENT);
}

__global__ __launch_bounds__(1024) void crf_init(const float* __restrict__ emit,
                                                 const float* __restrict__ strans,
                                                 u64* __restrict__ buf) {
  int tid = threadIdx.x;
  float a0 = strans[tid] + emit[tid];
  buf[tid] = pack_tag(0u, a0);
}

__global__ __launch_bounds__(1024) void crf_score(const float* __restrict__ emit,
                                                  const int* __restrict__ y,
                                                  const float* __restrict__ trans,
                                                  const float* __restrict__ strans,
                                                  const float* __restrict__ etrans,
                                                  float* __restrict__ ws) {
  int tid = threadIdx.x;
  float local = 0.f;
  for (int t = tid; t < T_LEN; t += 1024) {
    int yt = y[t];
    local += emit[t * NT + yt];
    if (t > 0) local += trans[y[t - 1] * NT + yt];
  }
  if (tid == 0) local += strans[y[0]];
  if (tid == 1023) local += etrans[y[T_LEN - 1]];
#pragma unroll
  for (int o = 32; o; o >>= 1) local += __shfl_xor(local, o);
  __shared__ float sm[16];
  if ((tid & 63) == 0) sm[tid >> 6] = local;
  __syncthreads();
  if (tid == 0) {
    float s = 0.f;
    for (int i = 0; i < 16; ++i) s += sm[i];
    ws[4096] = s;
  }
}

__global__ __launch_bounds__(NTHR, 1) void crf_scan(const float* __restrict__ emit,
                                                    const float* __restrict__ trans,
                                                    u64* buf) {
  const int tid = threadIdx.x;      // 0..255
  const int w   = tid >> 6;         // wave 0..3
  const int l   = tid & 63;
  const int c   = l & 3;            // col within wave
  const int js  = l >> 2;           // j-slice 0..15 (64 j's each)
  const int col = blockIdx.x * CPB + 4 * w + c;

  u64* buf0 = buf;
  u64* buf1 = buf + NT;

  // P fragment: p[4i+x] = exp(trans[j,col]), j = 64*js + ((4i+4*js)&63) + x.
  // The 4*js stagger -> GEMV float4 reads alias banks only 2-way (free).
  float p[64];
#pragma unroll
  for (int i = 0; i < 16; ++i) {
    int off = (4 * i + 4 * js) & 63;
#pragma unroll
    for (int x = 0; x < 4; ++x)
      p[4 * i + x] = __expf(trans[(64 * js + off + x) * NT + col]);
  }

  __shared__ __align__(16) float aS[2][NT];   // double-buffered by step parity
  __shared__ float wMaxS[2][4];               // lagged per-wave maxes, by parity

  const int i0 = tid, i1 = tid + 256, i2 = tid + 512, i3 = tid + 768;

  // preamble: prime wMaxS[0] from alpha_0 (tag 0 published by crf_init)
  {
    float a0 = __uint_as_float((u32)ld_tag(buf0 + i0));
    float a1 = __uint_as_float((u32)ld_tag(buf0 + i1));
    float a2 = __uint_as_float((u32)ld_tag(buf0 + i2));
    float a3 = __uint_as_float((u32)ld_tag(buf0 + i3));
    float m4 = fmaxf(fmaxf(a0, a1), fmaxf(a2, a3));
#pragma unroll
    for (int o = 1; o < 64; o <<= 1) m4 = fmaxf(m4, __shfl_xor(m4, o));
    if (l == 0) wMaxS[0][w] = m4;
  }
  float eCur = emit[1 * NT + col];
  __syncthreads();

  for (int t = 1; t < T_LEN; ++t) {
    u64* bIn  = (t & 1) ? buf0 : buf1;   // holds tag t-1
    u64* bOut = (t & 1) ? buf1 : buf0;   // receives tag t
    const u32 want = (u32)(t - 1);

    // lagged block-uniform scale (max of alpha_{t-2}); exp headroom is huge
    const float* wm = wMaxS[(t - 1) & 1];
    float M = fmaxf(fmaxf(wm[0], wm[1]), fmaxf(wm[2], wm[3]));

    // poll 4 tagged words, independently in flight
    u64 w0 = ld_tag(bIn + i0), w1 = ld_tag(bIn + i1);
    u64 w2 = ld_tag(bIn + i2), w3 = ld_tag(bIn + i3);
    for (;;) {
      bool s0 = (u32)(w0 >> 32) != want;
      bool s1 = (u32)(w1 >> 32) != want;
      bool s2 = (u32)(w2 >> 32) != want;
      bool s3 = (u32)(w3 >> 32) != want;
      if (!(s0 | s1 | s2 | s3)) break;
      if (s0) w0 = ld_tag(bIn + i0);
      if (s1) w1 = ld_tag(bIn + i1);
      if (s2) w2 = ld_tag(bIn + i2);
      if (s3) w3 = ld_tag(bIn + i3);
    }
    float a0 = __uint_as_float((u32)w0);
    float a1 = __uint_as_float((u32)w1);
    float a2 = __uint_as_float((u32)w2);
    float a3 = __uint_as_float((u32)w3);

    float* aP = aS[t & 1];
    aP[i0] = __expf(a0 - M);
    aP[i1] = __expf(a1 - M);
    aP[i2] = __expf(a2 - M);
    aP[i3] = __expf(a3 - M);

    // next step's lagged max (off the critical tail: written pre-barrier)
    float m4 = fmaxf(fmaxf(a0, a1), fmaxf(a2, a3));
#pragma unroll
    for (int o = 1; o < 64; o <<= 1) m4 = fmaxf(m4, __shfl_xor(m4, o));
    if (l == 0) wMaxS[t & 1][w] = m4;

    // deep emit prefetch: in flight across barrier + GEMV + next poll
    int tn = (t + 1 < T_LEN) ? t + 1 : t;
    float eNext = emit[tn * NT + col];

    __syncthreads();   // the ONLY barrier per step

    // GEMV: 16 broadcast float4 reads + 64 FMA; wave-local columns
    const float4* aV = (const float4*)aP;
    float s = 0.f;
#pragma unroll
    for (int i = 0; i < 16; ++i) {
      float4 a4 = aV[16 * js + ((i + js) & 15)];
      s = fmaf(a4.x, p[4 * i + 0], s);
      s = fmaf(a4.y, p[4 * i + 1], s);
      s = fmaf(a4.z, p[4 * i + 2], s);
      s = fmaf(a4.w, p[4 * i + 3], s);
    }
    // in-wave reduction over the 16 lanes sharing this column (bits 2..5)
    s += __shfl_xor(s, 4);
    s += __shfl_xor(s, 8);
    s += __shfl_xor(s, 16);
    s += __shfl_xor(s, 32);

    if (l < 4)  // one lane per column publishes
      st_tag(bOut + col, pack_tag((u32)t, eCur + M + __logf(s)));

    eCur = eNext;
  }
}

__global__ __launch_bounds__(1024) void crf_final(const float* __restrict__ etrans,
                                                  const u64* __restrict__ buf,
                                                  const float* __restrict__ ws,
                                                  float* __restrict__ out) {
  int tid = threadIdx.x;
  // final alpha (t = 16383, odd) lives in buf1
  float v = __uint_as_float((u32)buf[NT + tid]) + etrans[tid];
  float m = v;
#pragma unroll
  for (int o = 32; o; o >>= 1) m = fmaxf(m, __shfl_xor(m, o));
  __shared__ float sm[16];
  __shared__ float sM;
  if ((tid & 63) == 0) sm[tid >> 6] = m;
  __syncthreads();
  if (tid == 0) {
    float mm = sm[0];
    for (int i = 1; i < 16; ++i) mm = fmaxf(mm, sm[i]);
    sM = mm;
  }
  __syncthreads();
  float Mv = sM;
  float s = __expf(v - Mv);
#pragma unroll
  for (int o = 32; o; o >>= 1) s += __shfl_xor(s, o);
  __shared__ float ss[16];
  if ((tid & 63) == 0) ss[tid >> 6] = s;
  __syncthreads();
  if (tid == 0) {
    float tot = 0.f;
    for (int i = 0; i < 16; ++i) tot += ss[i];
    float logZ = Mv + __logf(tot);
    out[0] = logZ - ws[4096];
  }
}

extern "C" void kernel_launch(void* const* d_in, const int* in_sizes, int n_in,
                              void* d_out, int out_size, void* d_ws, size_t ws_size,
                              hipStream_t stream) {
  const float* emit = (const float*)d_in[0];
  const int* y = (const int*)d_in[1];
  const float* trans = (const float*)d_in[2];
  const float* strans = (const float*)d_in[3];
  const float* etrans = (const float*)d_in[4];
  u64* buf = (u64*)d_ws;
  float* ws = (float*)d_ws;
  float* out = (float*)d_out;

  crf_init<<<1, 1024, 0, stream>>>(emit, strans, buf);
  crf_score<<<1, 1024, 0, stream>>>(emit, y, trans, strans, etrans, ws);
  crf_scan<<<NBLK, NTHR, 0, stream>>>(emit, trans, buf);
  crf_final<<<1, 1024, 0, stream>>>(etrans, buf, ws, out);
}

// Round 5
// 25338.303 us; speedup vs baseline: 1.4363x; 1.4363x over previous
//
#include <hip/hip_runtime.h>

#define T_LEN 16384
#define NT 1024
#define NBLK 256
#define CPB 4       // columns per block
#define NTHR 64     // ONE wave -> no __syncthreads anywhere in the step loop

typedef unsigned long long u64;
typedef unsigned int u32;

// ws layout:
//   u64 buf0[1024] @ bytes [0,8192)      tagged alpha, even parity
//   u64 buf1[1024] @ bytes [8192,16384)  tagged alpha, odd parity
//   float gold     @ float index 4096
// tagged word = (step_tag << 32) | float_bits

__device__ __forceinline__ u64 pack_tag(u32 tag, float v) {
  return ((u64)tag << 32) | (u64)__float_as_uint(v);
}
__device__ __forceinline__ u64 ld_tag(const u64* p) {
  return __hip_atomic_load(p, __ATOMIC_RELAXED, __HIP_MEMORY_SCOPE_AGENT);
}
__device__ __forceinline__ void st_tag(u64* p, u64 v) {
  __hip_atomic_store(p, v, __ATOMIC_RELAXED, __HIP_MEMORY_SCOPE_AGENT);
}

__global__ __launch_bounds__(1024) void crf_init(const float* __restrict__ emit,
                                                 const float* __restrict__ strans,
                                                 u64* __restrict__ buf) {
  int tid = threadIdx.x;
  float a0 = strans[tid] + emit[tid];
  buf[tid] = pack_tag(0u, a0);
}

__global__ __launch_bounds__(1024) void crf_score(const float* __restrict__ emit,
                                                  const int* __restrict__ y,
                                                  const float* __restrict__ trans,
                                                  const float* __restrict__ strans,
                                                  const float* __restrict__ etrans,
                                                  float* __restrict__ ws) {
  int tid = threadIdx.x;
  float local = 0.f;
  for (int t = tid; t < T_LEN; t += 1024) {
    int yt = y[t];
    local += emit[t * NT + yt];
    if (t > 0) local += trans[y[t - 1] * NT + yt];
  }
  if (tid == 0) local += strans[y[0]];
  if (tid == 1023) local += etrans[y[T_LEN - 1]];
#pragma unroll
  for (int o = 32; o; o >>= 1) local += __shfl_xor(local, o);
  __shared__ float sm[16];
  if ((tid & 63) == 0) sm[tid >> 6] = local;
  __syncthreads();
  if (tid == 0) {
    float s = 0.f;
    for (int i = 0; i < 16; ++i) s += sm[i];
    ws[4096] = s;
  }
}

__global__ __launch_bounds__(NTHR, 1) void crf_scan(const float* __restrict__ emit,
                                                    const float* __restrict__ trans,
                                                    u64* buf) {
  const int l   = threadIdx.x;      // 0..63, one wave
  const int c   = l & 3;            // column within block
  const int js  = l >> 2;           // j-slice 0..15 (64 j's each)
  const int col = blockIdx.x * CPB + c;

  u64* buf0 = buf;
  u64* buf1 = buf + NT;

  // P fragment: p[4i+x] = exp(trans[j,col]), j = 64*js + ((4i+4*js)&63) + x.
  // 4*js stagger -> GEMV b128 reads alias LDS banks only 2-way (free, m136).
  float p[64];
#pragma unroll
  for (int i = 0; i < 16; ++i) {
    int off = (4 * i + 4 * js) & 63;
#pragma unroll
    for (int x = 0; x < 4; ++x)
      p[4 * i + x] = __expf(trans[(64 * js + off + x) * NT + col]);
  }

  __shared__ __align__(16) float aS[NT];   // single wave: no races, no dbuf

  // initial scale M = exact max of alpha_0 (tag 0 from crf_init)
  float M;
  {
    float m = -1e30f;
#pragma unroll
    for (int i = 0; i < 16; ++i) {
      u64 wv = ld_tag(buf0 + i * 64 + l);
      m = fmaxf(m, __uint_as_float((u32)wv));
    }
#pragma unroll
    for (int o = 1; o < 64; o <<= 1) m = fmaxf(m, __shfl_xor(m, o));
    M = m;
  }
  float eCur = emit[NT + col];

  for (int t = 1; t < T_LEN; ++t) {
    u64* bIn  = (t & 1) ? buf0 : buf1;   // holds tag t-1
    u64* bOut = (t & 1) ? buf1 : buf0;   // receives tag t
    const u32 want = (u32)(t - 1);

    // emit prefetch for t+1: issued at the top, consumed next iteration.
    // No barrier exists to force vmcnt(0) on it -> latency fully hidden.
    int tn = (t + 1 < T_LEN) ? t + 1 : t;
    float eNext = emit[tn * NT + col];

    // poll: 16 coalesced tagged words per lane (lane l owns j = i*64 + l)
    u64 wv[16];
    bool done;
    do {
#pragma unroll
      for (int i = 0; i < 16; ++i) wv[i] = ld_tag(bIn + i * 64 + l);
      done = true;
#pragma unroll
      for (int i = 0; i < 16; ++i) done &= ((u32)(wv[i] >> 32) == want);
    } while (!done);

    // stage exp(alpha - M) to LDS; wave-lockstep => in-order LDS, no barrier
#pragma unroll
    for (int i = 0; i < 16; ++i)
      aS[i * 64 + l] = __expf(__uint_as_float((u32)wv[i]) - M);

    // GEMV: 16 broadcast float4 reads + 64 FMA for this lane's (col, j-slice)
    const float4* aV = (const float4*)aS;
    float s = 0.f;
#pragma unroll
    for (int i = 0; i < 16; ++i) {
      float4 a4 = aV[16 * js + ((i + js) & 15)];
      s = fmaf(a4.x, p[4 * i + 0], s);
      s = fmaf(a4.y, p[4 * i + 1], s);
      s = fmaf(a4.z, p[4 * i + 2], s);
      s = fmaf(a4.w, p[4 * i + 3], s);
    }
    // reduce over the 16 lanes sharing this column (lane bits 2..5)
    s += __shfl_xor(s, 4);
    s += __shfl_xor(s, 8);
    s += __shfl_xor(s, 16);
    s += __shfl_xor(s, 32);

    float anew = eCur + M + __logf(s);
    if (l < 4)  // one lane per column publishes (32 B coalesced)
      st_tag(bOut + col, pack_tag((u32)t, anew));

    // lag-1 block-local scale for next step (post-store: off critical path)
    float m2 = fmaxf(anew, __shfl_xor(anew, 1));
    m2 = fmaxf(m2, __shfl_xor(m2, 2));
    M = m2;
    eCur = eNext;
  }
}

__global__ __launch_bounds__(1024) void crf_final(const float* __restrict__ etrans,
                                                  const u64* __restrict__ buf,
                                                  const float* __restrict__ ws,
                                                  float* __restrict__ out) {
  int tid = threadIdx.x;
  // final alpha (t = 16383, odd) lives in buf1
  float v = __uint_as_float((u32)buf[NT + tid]) + etrans[tid];
  float m = v;
#pragma unroll
  for (int o = 32; o; o >>= 1) m = fmaxf(m, __shfl_xor(m, o));
  __shared__ float sm[16];
  __shared__ float sM;
  if ((tid & 63) == 0) sm[tid >> 6] = m;
  __syncthreads();
  if (tid == 0) {
    float mm = sm[0];
    for (int i = 1; i < 16; ++i) mm = fmaxf(mm, sm[i]);
    sM = mm;
  }
  __syncthreads();
  float Mv = sM;
  float s = __expf(v - Mv);
#pragma unroll
  for (int o = 32; o; o >>= 1) s += __shfl_xor(s, o);
  __shared__ float ss[16];
  if ((tid & 63) == 0) ss[tid >> 6] = s;
  __syncthreads();
  if (tid == 0) {
    float tot = 0.f;
    for (int i = 0; i < 16; ++i) tot += ss[i];
    float logZ = Mv + __logf(tot);
    out[0] = logZ - ws[4096];
  }
}

extern "C" void kernel_launch(void* const* d_in, const int* in_sizes, int n_in,
                              void* d_out, int out_size, void* d_ws, size_t ws_size,
                              hipStream_t stream) {
  const float* emit = (const float*)d_in[0];
  const int* y = (const int*)d_in[1];
  const float* trans = (const float*)d_in[2];
  const float* strans = (const float*)d_in[3];
  const float* etrans = (const float*)d_in[4];
  u64* buf = (u64*)d_ws;
  float* ws = (float*)d_ws;
  float* out = (float*)d_out;

  crf_init<<<1, 1024, 0, stream>>>(emit, strans, buf);
  crf_score<<<1, 1024, 0, stream>>>(emit, y, trans, strans, etrans, ws);
  crf_scan<<<NBLK, NTHR, 0, stream>>>(emit, trans, buf);
  crf_final<<<1, 1024, 0, stream>>>(etrans, buf, ws, out);
}